// Round 14
// baseline (224.772 us; speedup 1.0000x reference)
//
#include <hip/hip_runtime.h>
#include <math.h>

// ---------------- problem constants (static shapes) ----------------
#define NIMG 8
#define ATOT 65472
#define KTOT 6960          // 2000+2000+2000+768+192
#define POST 2000
#define TILES_PER_IMG 1668 // 528*3 + 78 + 6
#define NTILES (NIMG*TILES_PER_IMG)
#define ESEG 1024          // edges per (task,gi) segment cap
#define BUFCAP 3072        // 12-bit-threshold candidate cap (observed ~2500)
// Exact tie boundary: f32_div(inter,uni) > 0.7f  <=>  inter/uni >= M_TIE.
// M_TIE = midpoint(0.7f, nextafterf(0.7f)) = 23488103/2^25; ties-to-even sends
// the midpoint UP. (double)inter >= M_TIE*(double)uni is exact: 25b+24b <= 53b.
// Validated bit-exact vs division predicate in rounds 4-13 (absmax 0.0).
#define M_TIE 0.7000000178813934326171875
// wave-local LDS ordering (one-wave NMS: no cross-wave state => no s_barrier)
#define WAVE_SYNC() asm volatile("s_waitcnt lgkmcnt(0)" ::: "memory")

__constant__ int c_NAPL[5]  = {49152,12288,3072,768,192};
__constant__ int c_LOFF[5]  = {0,49152,61440,64512,65280};
__constant__ int c_KSEL[5]  = {2000,2000,2000,768,192};
__constant__ int c_CBASE[5] = {0,2000,4000,6000,6768};
__constant__ int c_GLVL[5]  = {32,32,32,12,3};      // ceil(k/64)
__constant__ int c_TILEPFX[6] = {0,528,1056,1584,1662,1668};

// monotone float->uint map (order-preserving for all finite floats)
__device__ __forceinline__ unsigned f2u(float f){
  unsigned b = __float_as_uint(f);
  return (b & 0x80000000u) ? ~b : (b | 0x80000000u);
}
// composite key: (value desc, global idx asc) when sorted descending
__device__ __forceinline__ unsigned long long mkkey(unsigned u, unsigned gidx){
  return ((unsigned long long)u << 32) | (unsigned long long)(0xFFFFFFFFu - gidx);
}
__device__ __forceinline__ unsigned long long shflx64(unsigned long long v, int m){
  int lo = __shfl_xor((int)(unsigned)v, m);
  int hi = __shfl_xor((int)(unsigned)(v >> 32), m);
  return ((unsigned long long)(unsigned)hi << 32) | (unsigned)lo;
}
// count of elements > x in a descending-sorted 64-run (6-step binary search)
__device__ __forceinline__ int cntGreater64(const unsigned long long* a,
                                            unsigned long long x){
  int lo = 0, hi = 64;
  while (lo < hi){
    int mid = (lo + hi) >> 1;
    if (a[mid] > x) lo = mid + 1; else hi = mid;
  }
  return lo;
}

// ---------------- K1: select = hist12 -> b12 -> append -> wave-sort + rank-merge ----------------
// One block per (img,lvl). Appended set ((u>>20) >= b12) is a superset of
// top-k and every excluded key is strictly smaller (bin dominance). Keys are
// unique => global rank (= own-chunk pos + sum of cntGreater over other sorted
// 64-chunks) is an exact permutation; ranks < k == exact top-k (value desc,
// idx asc) => bit-identical to the previous sorted-emit.
extern "C" __global__ void __launch_bounds__(1024)
k_select(const float* __restrict__ prop, const float* __restrict__ obj,
         unsigned long long* __restrict__ cand, float4* __restrict__ cbox,
         unsigned* __restrict__ zzone){   // zzone = ecnt (1280 words)
  __shared__ unsigned long long sb[BUFCAP];  // 24 KB: unsorted -> 64-sorted runs
  __shared__ unsigned hist[4096];            // 16 KB
  __shared__ unsigned scan[1024];            // 4 KB
  __shared__ unsigned s_b12, s_cnt;
  int task = blockIdx.x, img = task/5, lvl = task%5;
  int n = c_NAPL[lvl], k = c_KSEL[lvl], tid = threadIdx.x;
  if (task == 0)
    for (int i = tid; i < 1280; i += 1024) zzone[i] = 0u;

  const float4* o4 = (const float4*)(obj + (size_t)img*ATOT + c_LOFF[lvl]);
  int n4 = n >> 2;
  unsigned kk = (unsigned)k;
  unsigned b12v = 0u;
  if (k < n){
    for (int i = tid; i < 4096; i += 1024) hist[i] = 0u;
    __syncthreads();
    // sweep 1: 12-bit histogram
    for (int i = tid; i < n4; i += 1024){
      float4 v = o4[i];
      atomicAdd(&hist[f2u(v.x) >> 20], 1u);
      atomicAdd(&hist[f2u(v.y) >> 20], 1u);
      atomicAdd(&hist[f2u(v.z) >> 20], 1u);
      atomicAdd(&hist[f2u(v.w) >> 20], 1u);
    }
    __syncthreads();
    // parallel suffix-scan: b12 = largest bin b with suf(b) >= k
    unsigned own[4]; unsigned s = 0;
    int b0 = tid*4;
    #pragma unroll
    for (int j = 0; j < 4; ++j){ own[j] = hist[b0+j]; s += own[j]; }
    scan[tid] = s;
    __syncthreads();
    for (int d = 1; d < 1024; d <<= 1){
      unsigned v = (tid + d < 1024) ? scan[tid + d] : 0u;
      __syncthreads();
      scan[tid] += v;
      __syncthreads();
    }
    {
      unsigned R = scan[tid] - s;
      unsigned sufn = R;
      #pragma unroll
      for (int j = 3; j >= 0; --j){
        unsigned sufj = sufn + own[j];
        if (sufj >= kk && sufn < kk) s_b12 = (unsigned)(b0 + j);
        sufn = sufj;
      }
    }
    __syncthreads();
    b12v = s_b12;
  }
  if (tid == 0) s_cnt = 0u;
  __syncthreads();
  // sweep 2: append (u>>20) >= b12 (wave-aggregated, one LDS atomic per wave)
  int abase = c_LOFF[lvl];
  int lane = tid & 63, wv = tid >> 6;
  for (int i = tid; i < n4; i += 1024){
    float4 v = o4[i];
    float vv[4] = {v.x, v.y, v.z, v.w};
    #pragma unroll
    for (int c2 = 0; c2 < 4; ++c2){
      unsigned u = f2u(vv[c2]);
      bool pred = (u >> 20) >= b12v;
      unsigned long long bm = __ballot(pred);
      unsigned cw = (unsigned)__popcll(bm);
      unsigned basep = 0;
      if (lane == 0 && cw) basep = atomicAdd(&s_cnt, cw);
      basep = __shfl(basep, 0);
      if (pred){
        unsigned p = basep + (unsigned)__popcll(bm & ((1ull << lane) - 1ull));
        if (p < (unsigned)BUFCAP) sb[p] = mkkey(u, (unsigned)(abase + i*4 + c2));
      }
    }
  }
  __syncthreads();
  int cnt = (int)min(s_cnt, (unsigned)BUFCAP);
  int nch = (cnt + 63) >> 6;            // sorted 64-chunks (<= 48)
  for (int i = cnt + tid; i < nch*64; i += 1024) sb[i] = 0ull;  // zero-pad tail
  __syncthreads();
  // per-wave in-register bitonic sort (descending) of each 64-chunk: 21 stages,
  // zero barriers. Zeros sort to the tail.
  for (int c = wv; c < nch; c += 16){
    unsigned long long v = sb[c*64 + lane];
    #pragma unroll
    for (int s = 2; s <= 64; s <<= 1){
      #pragma unroll
      for (int st = s >> 1; st > 0; st >>= 1){
        unsigned long long p = shflx64(v, st);
        bool lower = (lane & st) == 0;
        bool descBlk = (lane & s) == 0;   // s=64: always true => full descending
        bool takeMax = (lower == descBlk);
        bool gt = v > p;
        v = (takeMax == gt) ? v : p;
      }
    }
    sb[c*64 + lane] = v;
  }
  __syncthreads();
  // rank-merge scatter: rank = own-chunk pos + sum cntGreater(other chunks).
  // Zeros (padding) rank >= cnt >= k => dropped. Ranks of real keys are a
  // permutation of [0,cnt); ranks < k written directly at final position.
  const float4* pr = (const float4*)(prop + (size_t)img*ATOT*4);
  size_t base = (size_t)img*KTOT + c_CBASE[lvl];
  int tot = nch*64;
  for (int e = tid; e < tot; e += 1024){
    unsigned long long x = sb[e];
    if (!x) continue;
    int rank = e & 63, myc = e >> 6;
    for (int c = 0; c < nch; ++c){
      if (c == myc) continue;
      rank += cntGreater64(sb + c*64, x);
    }
    if (rank < k){
      cand[base + rank] = x;
      unsigned gidx = 0xFFFFFFFFu - (unsigned)(x & 0xFFFFFFFFull);
      float4 p = pr[gidx];
      cbox[base + rank] = make_float4(fminf(fmaxf(p.x,0.f),512.f), fminf(fmaxf(p.y,0.f),512.f),
                                      fminf(fmaxf(p.z,0.f),512.f), fminf(fmaxf(p.w,0.f),512.f));
    }
  }
}

// ---------------- K2: IoU tiles with f32-bounds fast path -> edge lists; zero d_out ----------------
// Exact predicate preserved: inter >= 0.701f*uni implies hit (0.701*(1-2^-24) >
// M_TIE); inter < 0.699f*uni implies not-hit (0.699*(1+2^-24) < M_TIE);
// ambiguous lanes (ratio within ~1e-3 of 0.7, rare) take the exact f64 compare.
extern "C" __global__ void __launch_bounds__(64)
k_mask(const float4* __restrict__ cbox, unsigned* __restrict__ ecnt,
       unsigned* __restrict__ eseg, float4* __restrict__ out4, int out_n4){
  __shared__ float4 colb[64];
  __shared__ float  colA[64];
  int bid = blockIdx.x, lane = threadIdx.x;
  if (bid < 313){
    int i = bid*64 + lane;
    if (i < out_n4) out4[i] = make_float4(0.f,0.f,0.f,0.f);
  }
  int img = bid / TILES_PER_IMG, r = bid % TILES_PER_IMG;
  int lvl = 0;
  while (r >= c_TILEPFX[lvl + 1]) ++lvl;
  int t = r - c_TILEPFX[lvl];
  int G = c_GLVL[lvl], k = c_KSEL[lvl];
  int gi = 0;
  while (t >= G - gi){ t -= G - gi; ++gi; }
  int gj = gi + t;
  int task = img*5 + lvl;
  const float4* cb = cbox + (size_t)img*KTOT + c_CBASE[lvl];

  int jj = gj*64 + lane;
  float4 bb = (jj < k) ? cb[jj] : make_float4(0.f,0.f,0.f,0.f);
  colb[lane] = bb;
  colA[lane] = (bb.z - bb.x) * (bb.w - bb.y);
  __syncthreads();

  int i = gi*64 + lane;
  unsigned long long word = 0ull;
  if (i < k){
    float4 a = cb[i];
    float aarea = (a.z - a.x) * (a.w - a.y);
    for (int j = 0; j < 64; ++j){
      float4 b = colb[j];
      float ix = fminf(a.z, b.z) - fmaxf(a.x, b.x);
      float iy = fminf(a.w, b.w) - fmaxf(a.y, b.y);
      float inter = ix * iy;
      float uni = (aarea + colA[j]) - inter;
      bool base = (ix > 0.f) & (iy > 0.f);
      bool hi  = inter >= 0.701f * uni;
      bool lo  = inter <  0.699f * uni;
      bool hit = base & hi;
      bool amb = base & (!hi) & (!lo);
      if (__any(amb))
        hit = hit | (amb & ((double)inter >= M_TIE * (double)uni));
      word |= hit ? (1ull << j) : 0ull;
    }
    if (gi == gj)
      word &= (lane == 63) ? 0ull : (~0ull << (lane + 1));
  }
  int nb = __popcll(word);
  int pfx = nb;
  for (int d = 1; d < 64; d <<= 1){
    int v = __shfl_up(pfx, d);
    if (lane >= d) pfx += v;
  }
  int total = __shfl(pfx, 63);
  if (total > 0){
    unsigned base = 0;
    if (lane == 0) base = atomicAdd(&ecnt[task*32 + gi], (unsigned)total);
    base = __shfl(base, 0);
    unsigned idx = base + (unsigned)(pfx - nb);
    unsigned* ep = eseg + (size_t)(task*32 + gi)*ESEG;
    while (word){
      int j = __ffsll(word) - 1; word &= word - 1;
      if (idx < ESEG) ep[idx] = ((unsigned)i << 16) | (unsigned)(gj*64 + j);
      ++idx;
    }
  }
}

// ---------------- K3: NMS word-sweep; 4-wave staging, 1-wave exact sweep ----------------
// Staging and compaction use all 4 waves (separated from the sweep by
// __syncthreads). The sweep itself runs entirely in wave 0 on LDS state no
// other wave touches (round-7/11-validated): word w's keep bits are FINAL
// before its suppressions propagate => identical to sequential greedy NMS.
extern "C" __global__ void __launch_bounds__(256)
k_scan(const unsigned long long* __restrict__ cand, const unsigned* __restrict__ ecnt,
       const unsigned* __restrict__ eseg, unsigned long long* __restrict__ clist,
       unsigned* __restrict__ ccnt){
  __shared__ unsigned ledge[6144];          // 24 KB edge cache
  __shared__ unsigned soff[33], wpfx[33];
  __shared__ unsigned long long sm[64];     // intra-word suppression rows
  __shared__ unsigned long long remW[32], keepW[32];
  __shared__ unsigned long long s_hasI;
  int task = blockIdx.x, img = task / 5, lvl = task % 5;
  int k = c_KSEL[lvl], nW = c_GLVL[lvl], tid = threadIdx.x;

  if (tid == 0){
    unsigned s = 0;
    for (int w = 0; w < nW; ++w){ soff[w] = s; s += min(ecnt[task*32 + w], (unsigned)ESEG); }
    soff[nW] = s;
  }
  if (tid < 32) remW[tid] = 0ull;
  __syncthreads();
  // stage all edges into LDS with 4 waves (global fallback beyond 6144)
  for (int w = 0; w < nW; ++w){
    unsigned c = soff[w+1] - soff[w];
    const unsigned* ep = eseg + (size_t)(task*32 + w)*ESEG;
    for (unsigned e = tid; e < c; e += 256){
      unsigned p = soff[w] + e;
      if (p < 6144u) ledge[p] = ep[e];
    }
  }
  __syncthreads();

  if (tid < 64){     // wave 0 runs the exact sequential-greedy word-sweep
    int lane = tid;
    for (int w = 0; w < nW; ++w){
      unsigned c = soff[w+1] - soff[w];
      if (c == 0) continue;
      const unsigned* ep = eseg + (size_t)(task*32 + w)*ESEG;
      sm[lane] = 0ull;
      if (lane == 0) s_hasI = 0ull;
      WAVE_SYNC();
      for (unsigned e = lane; e < c; e += 64){
        unsigned p = soff[w] + e;
        unsigned ed = (p < 6144u) ? ledge[p] : ep[e];
        int i = (int)(ed >> 16), j = (int)(ed & 0xFFFFu);
        if ((j >> 6) == w){
          atomicOr(&sm[i & 63], 1ull << (j & 63));
          atomicOr(&s_hasI, 1ull << (i & 63));
        }
      }
      WAVE_SYNC();
      if (lane == 0){
        unsigned long long r = remW[w];
        unsigned long long x = s_hasI & ~r;
        while (x){
          int i = __ffsll(x) - 1;
          r |= sm[i];
          x &= ~(1ull << i);
          x &= ~r;
        }
        remW[w] = r;
      }
      WAVE_SYNC();
      unsigned long long keep_w = ~remW[w];
      for (unsigned e = lane; e < c; e += 64){
        unsigned p = soff[w] + e;
        unsigned ed = (p < 6144u) ? ledge[p] : ep[e];
        int i = (int)(ed >> 16), j = (int)(ed & 0xFFFFu), wj = j >> 6;
        if (wj != w && ((keep_w >> (i & 63)) & 1ull))
          atomicOr(&remW[wj], 1ull << (j & 63));
      }
      WAVE_SYNC();
    }
    if (lane < 32){
      unsigned long long v = 0ull;
      if (lane < nW){
        int rem = k - lane*64;
        v = (rem >= 64) ? ~0ull : ((1ull << rem) - 1ull);
      }
      keepW[lane] = v & ~remW[lane];
    }
    WAVE_SYNC();
    if (lane == 0){
      unsigned s = 0;
      for (int w = 0; w < nW; ++w){ wpfx[w] = s; s += (unsigned)__popcll(keepW[w]); }
      ccnt[task] = s;
    }
  }
  __syncthreads();
  // compact kept candidates with all 4 waves (preserves sorted order)
  size_t base = (size_t)img*KTOT + c_CBASE[lvl];
  for (int i = tid; i < k; i += 256){
    unsigned long long w = keepW[i >> 6];
    if ((w >> (i & 63)) & 1ull){
      unsigned long long lowmask = (i & 63) ? ((1ull << (i & 63)) - 1ull) : 0ull;
      unsigned rank = wpfx[i >> 6] + (unsigned)__popcll(w & lowmask);
      clist[base + rank] = cand[base + i];
    }
  }
}

// ---------------- K4: 5-way rank merge (no sort), 8 blocks/image ----------------
__device__ __forceinline__ int cntGreater(const unsigned long long* base, int len,
                                          unsigned long long x){
  int lo = 0, hi = len;          // descending array, unique keys
  while (lo < hi){
    int mid = (lo + hi) >> 1;
    if (base[mid] > x) lo = mid + 1; else hi = mid;
  }
  return lo;
}

extern "C" __global__ void __launch_bounds__(1024)
k_merge(const float* __restrict__ prop, const float* __restrict__ obj,
        const unsigned long long* __restrict__ clist, const unsigned* __restrict__ ccnt,
        float* __restrict__ out){
  __shared__ unsigned long long keys[KTOT];   // ~54.4 KB
  __shared__ int loff[6], lcnt[5];
  int img = blockIdx.x >> 3, eighth = blockIdx.x & 7, tid = threadIdx.x;
  if (tid == 0){
    int s = 0;
    for (int l = 0; l < 5; ++l){ lcnt[l] = (int)ccnt[img*5 + l]; loff[l] = s; s += lcnt[l]; }
    loff[5] = s;
  }
  __syncthreads();
  for (int l = 0; l < 5; ++l){
    size_t gb = (size_t)img*KTOT + c_CBASE[l];
    int c = lcnt[l], lo = loff[l];
    for (int e = tid; e < c; e += 1024) keys[lo + e] = clist[gb + e];
  }
  __syncthreads();
  const float4* pr = (const float4*)(prop + (size_t)img*ATOT*4);
  const float*  o  = obj + (size_t)img*ATOT;
  float* ob = out + (size_t)img*POST*4;
  float* os = out + (size_t)NIMG*POST*4 + (size_t)img*POST;
  int tot = loff[5];
  for (int tt = tid; ; tt += 1024){
    int t = 8*tt + eighth;
    if (t >= tot) break;
    int lvl = 0;
    while (t >= loff[lvl + 1]) ++lvl;
    unsigned long long x = keys[t];
    int pos = t - loff[lvl];
    for (int l = 0; l < 5; ++l){
      if (l == lvl) continue;
      pos += cntGreater(keys + loff[l], lcnt[l], x);
    }
    if (pos < POST){
      unsigned gidx = 0xFFFFFFFFu - (unsigned)(x & 0xFFFFFFFFull);
      float4 p = pr[gidx];
      ob[pos*4 + 0] = fminf(fmaxf(p.x, 0.f), 512.f);
      ob[pos*4 + 1] = fminf(fmaxf(p.y, 0.f), 512.f);
      ob[pos*4 + 2] = fminf(fmaxf(p.z, 0.f), 512.f);
      ob[pos*4 + 3] = fminf(fmaxf(p.w, 0.f), 512.f);
      double sgm = 1.0 / (1.0 + exp(-(double)o[gidx]));  // correctly-rounded f32 sigmoid
      os[pos] = (float)sgm;
    }
  }
}

// ---------------- launch ----------------
extern "C" void kernel_launch(void* const* d_in, const int* in_sizes, int n_in,
                              void* d_out, int out_size, void* d_ws, size_t ws_size,
                              hipStream_t stream){
  const float* prop = (const float*)d_in[0];
  const float* obj  = (const float*)d_in[1];
  char* ws = (char*)d_ws;
  // ws layout (bytes):
  unsigned*           ecnt = (unsigned*)(ws);                        // 40*32*4 = 5120
  unsigned*           ccnt = (unsigned*)(ws + 5120);                 // 160 -> 5280 (pad 5632)
  unsigned long long* cand = (unsigned long long*)(ws + 5632);       // 445440 -> 451072
  unsigned long long* clist= (unsigned long long*)(ws + 451072);     // 445440 -> 896512
  float4*             cbox = (float4*)(ws + 896512);                 // 890880 -> 1787392
  unsigned*           eseg = (unsigned*)(ws + 1787392);              // 5242880 -> 7030272

  int out_n4 = out_size / 4;   // 80000 floats = 20000 float4
  hipLaunchKernelGGL(k_select, dim3(40),  dim3(1024), 0, stream, prop, obj, cand, cbox, ecnt);
  hipLaunchKernelGGL(k_mask,   dim3(NTILES), dim3(64), 0, stream, cbox, ecnt, eseg,
                     (float4*)d_out, out_n4);
  hipLaunchKernelGGL(k_scan,   dim3(40),  dim3(256),  0, stream, cand, ecnt, eseg, clist, ccnt);
  hipLaunchKernelGGL(k_merge,  dim3(64),  dim3(1024), 0, stream, prop, obj, clist, ccnt, (float*)d_out);
}

// Round 15
// 184.909 us; speedup vs baseline: 1.2156x; 1.2156x over previous
//
#include <hip/hip_runtime.h>
#include <math.h>

// ---------------- problem constants (static shapes) ----------------
#define NIMG 8
#define ATOT 65472
#define KTOT 6960          // 2000+2000+2000+768+192
#define POST 2000
#define TILES_PER_IMG 1668 // 528*3 + 78 + 6
#define NTILES (NIMG*TILES_PER_IMG)
#define ESEG 1024          // edges per (task,gi) segment cap
// Exact tie boundary: f32_div(inter,uni) > 0.7f  <=>  inter/uni >= M_TIE.
// M_TIE = midpoint(0.7f, nextafterf(0.7f)) = 23488103/2^25; ties-to-even sends
// the midpoint UP. (double)inter >= M_TIE*(double)uni is exact: 25b+24b <= 53b.
// Validated bit-exact vs division predicate in rounds 4-14 (absmax 0.0).
#define M_TIE 0.7000000178813934326171875
// LDS padding for the u64 bitonic: +1 slot per 32 elements
#define PAD(i) ((i) + ((i) >> 5))
// wave-local LDS ordering (one-wave NMS: no cross-wave state => no s_barrier)
#define WAVE_SYNC() asm volatile("s_waitcnt lgkmcnt(0)" ::: "memory")

__constant__ int c_NAPL[5]  = {49152,12288,3072,768,192};
__constant__ int c_LOFF[5]  = {0,49152,61440,64512,65280};
__constant__ int c_KSEL[5]  = {2000,2000,2000,768,192};
__constant__ int c_CBASE[5] = {0,2000,4000,6000,6768};
__constant__ int c_GLVL[5]  = {32,32,32,12,3};      // ceil(k/64)
__constant__ int c_TILEPFX[6] = {0,528,1056,1584,1662,1668};

// monotone float->uint map (order-preserving for all finite floats)
__device__ __forceinline__ unsigned f2u(float f){
  unsigned b = __float_as_uint(f);
  return (b & 0x80000000u) ? ~b : (b | 0x80000000u);
}
// composite key: (value desc, global idx asc) when sorted descending
__device__ __forceinline__ unsigned long long mkkey(unsigned u, unsigned gidx){
  return ((unsigned long long)u << 32) | (unsigned long long)(0xFFFFFFFFu - gidx);
}
__device__ __forceinline__ unsigned long long shflx64(unsigned long long v, int m){
  int lo = __shfl_xor((int)(unsigned)v, m);
  int hi = __shfl_xor((int)(unsigned)(v >> 32), m);
  return ((unsigned long long)(unsigned)hi << 32) | (unsigned)lo;
}
// one bitonic compare-exchange substage across lanes (R14-validated pattern);
// flag convention identical to the LDS bitonic: desc block iff (elem&size)==0
__device__ __forceinline__ unsigned long long bstep(unsigned long long v, int elem,
                                                    int size, int st){
  unsigned long long p = shflx64(v, st);
  bool lower = (elem & st) == 0;
  bool desc  = (elem & size) == 0;
  bool takeMax = (lower == desc);
  bool gt = v > p;
  return (takeMax == gt) ? v : p;
}

// ---------------- K1: fused select; register-blocked bitonic ----------------
// Front half (hist12 -> suffix-scan b12 -> refine8 sweep -> t20 -> wave-
// aggregated append) verbatim from round 12 (measured, absmax 0.0). Sort:
// lane l of wave w owns elements 128w+l and 128w+l+64; all strides <= 64 run
// in registers via shfl_xor (51 of 66 substages, zero barriers/LDS); only
// strides >= 128 (10 substages) go through LDS. Identical sorting network =>
// identical permutation => bit-identical output. Element index == final rank,
// so emit happens straight from registers.
extern "C" __global__ void __launch_bounds__(1024)
k_select(const float* __restrict__ prop, const float* __restrict__ obj,
         unsigned long long* __restrict__ cand, float4* __restrict__ cbox,
         unsigned* __restrict__ zzone){   // zzone = ecnt (1280 words)
  __shared__ unsigned long long sb[2112];  // padded sort buffer (16.9 KB)
  __shared__ unsigned hist[4096];          // 16 KB
  __shared__ unsigned scan[1024];          // 4 KB
  __shared__ unsigned h8[256];
  __shared__ unsigned s_b12, s_cumAbove, s_t20, s_cnt;
  int task = blockIdx.x, img = task/5, lvl = task%5;
  int n = c_NAPL[lvl], k = c_KSEL[lvl], tid = threadIdx.x;
  if (task == 0)
    for (int i = tid; i < 1280; i += 1024) zzone[i] = 0u;

  const float4* o4 = (const float4*)(obj + (size_t)img*ATOT + c_LOFF[lvl]);
  int n4 = n >> 2;                         // all level sizes divisible by 4
  unsigned kk = (unsigned)k;
  unsigned T = 0u;                         // 20-bit threshold; 0 => append all
  if (k < n){
    for (int i = tid; i < 4096; i += 1024) hist[i] = 0u;
    if (tid < 256) h8[tid] = 0u;
    __syncthreads();
    // sweep 1: 12-bit histogram
    for (int i = tid; i < n4; i += 1024){
      float4 v = o4[i];
      atomicAdd(&hist[f2u(v.x) >> 20], 1u);
      atomicAdd(&hist[f2u(v.y) >> 20], 1u);
      atomicAdd(&hist[f2u(v.z) >> 20], 1u);
      atomicAdd(&hist[f2u(v.w) >> 20], 1u);
    }
    __syncthreads();
    // parallel suffix-scan: b12 = largest bin with suf(b) >= k
    unsigned own[4]; unsigned s = 0;
    int b0 = tid*4;
    #pragma unroll
    for (int j = 0; j < 4; ++j){ own[j] = hist[b0+j]; s += own[j]; }
    scan[tid] = s;
    __syncthreads();
    for (int d = 1; d < 1024; d <<= 1){
      unsigned v = (tid + d < 1024) ? scan[tid + d] : 0u;
      __syncthreads();
      scan[tid] += v;
      __syncthreads();
    }
    {
      unsigned R = scan[tid] - s;
      unsigned sufn = R;
      #pragma unroll
      for (int j = 3; j >= 0; --j){
        unsigned sufj = sufn + own[j];
        if (sufj >= kk && sufn < kk){ s_b12 = (unsigned)(b0 + j); s_cumAbove = sufn; }
        sufn = sufj;
      }
    }
    __syncthreads();
    unsigned b12 = s_b12;
    // sweep 2: 8-bit refinement within the boundary bin (L2-warm re-read)
    for (int i = tid; i < n4; i += 1024){
      float4 v = o4[i];
      unsigned ux = f2u(v.x), uy = f2u(v.y), uz = f2u(v.z), uw = f2u(v.w);
      if ((ux >> 20) == b12) atomicAdd(&h8[(ux >> 12) & 255u], 1u);
      if ((uy >> 20) == b12) atomicAdd(&h8[(uy >> 12) & 255u], 1u);
      if ((uz >> 20) == b12) atomicAdd(&h8[(uz >> 12) & 255u], 1u);
      if ((uw >> 20) == b12) atomicAdd(&h8[(uw >> 12) & 255u], 1u);
    }
    __syncthreads();
    if (tid < 256) scan[tid] = h8[tid];
    __syncthreads();
    for (int d = 1; d < 256; d <<= 1){
      unsigned v = 0;
      if (tid < 256) v = (tid + d < 256) ? scan[tid + d] : 0u;
      __syncthreads();
      if (tid < 256) scan[tid] += v;
      __syncthreads();
    }
    if (tid < 256){
      unsigned sufj = s_cumAbove + scan[tid];
      unsigned sufn = s_cumAbove + ((tid < 255) ? scan[tid + 1] : 0u);
      if (sufj >= kk && sufn < kk) s_t20 = (s_b12 << 8) | (unsigned)tid;
    }
    __syncthreads();
    T = s_t20;
  }
  if (tid == 0) s_cnt = 0u;
  __syncthreads();
  // sweep 3: append (u>>12) >= T — wave-aggregated, one LDS atomic per wave
  int abase = c_LOFF[lvl];
  int lane = tid & 63, wv = tid >> 6;
  for (int i = tid; i < n4; i += 1024){
    float4 v = o4[i];
    float vv[4] = {v.x, v.y, v.z, v.w};
    #pragma unroll
    for (int c2 = 0; c2 < 4; ++c2){
      unsigned u = f2u(vv[c2]);
      bool pred = (u >> 12) >= T;
      unsigned long long bm = __ballot(pred);
      unsigned cw = (unsigned)__popcll(bm);
      unsigned basep = 0;
      if (lane == 0 && cw) basep = atomicAdd(&s_cnt, cw);
      basep = __shfl(basep, 0);
      if (pred){
        unsigned p = basep + (unsigned)__popcll(bm & ((1ull << lane) - 1ull));
        if (p < 2048u) sb[PAD(p)] = mkkey(u, (unsigned)(abase + i*4 + c2));
      }
    }
  }
  __syncthreads();
  int cnt = (int)min(s_cnt, 2048u);
  int m = 256; while (m < k || m < cnt) m <<= 1;   // 2048 / 1024 / 256
  for (int i = cnt + tid; i < m; i += 1024) sb[PAD(i)] = 0ull;  // 0-key sorts last
  __syncthreads();

  // ---- register-blocked bitonic, descending ----
  int elemA = (wv << 7) | lane, elemB = elemA | 64;
  bool active = (elemA < m);
  unsigned long long va = 0ull, vb = 0ull;
  if (active){ va = sb[PAD(elemA)]; vb = sb[PAD(elemB)]; }
  if (active){
    // sizes 2..64: cross-lane in registers (desc flags from element bits)
    for (int size = 2; size <= 64; size <<= 1)
      for (int st = size >> 1; st >= 1; st >>= 1){
        va = bstep(va, elemA, size, st);
        vb = bstep(vb, elemB, size, st);
      }
    // size 128: stride 64 is the in-lane (va,vb) pair, then strides 32..1
    {
      bool desc = ((elemA & 128) == 0);
      unsigned long long mx = (va > vb) ? va : vb;
      unsigned long long mn = (va > vb) ? vb : va;
      va = desc ? mx : mn; vb = desc ? mn : mx;
      for (int st = 32; st >= 1; st >>= 1){
        va = bstep(va, elemA, 128, st);
        vb = bstep(vb, elemB, 128, st);
      }
    }
  }
  for (int S = 256; S <= m; S <<= 1){
    if (active){ sb[PAD(elemA)] = va; sb[PAD(elemB)] = vb; }
    __syncthreads();
    for (int st = S >> 1; st >= 128; st >>= 1){
      for (int t = tid; t < (m >> 1); t += 1024){
        int lo = t & (st - 1);
        int i  = ((t - lo) << 1) + lo;
        int j  = i + st;
        bool desc = ((i & S) == 0);
        unsigned long long x = sb[PAD(i)], y = sb[PAD(j)];
        if (desc ? (x < y) : (x > y)){ sb[PAD(i)] = y; sb[PAD(j)] = x; }
      }
      __syncthreads();
    }
    if (active){
      va = sb[PAD(elemA)]; vb = sb[PAD(elemB)];
      bool desc = ((elemA & S) == 0);   // elemB has same bit for S >= 256
      unsigned long long mx = (va > vb) ? va : vb;
      unsigned long long mn = (va > vb) ? vb : va;
      va = desc ? mx : mn; vb = desc ? mn : mx;
      for (int st = 32; st >= 1; st >>= 1){
        va = bstep(va, elemA, S, st);
        vb = bstep(vb, elemB, S, st);
      }
    }
  }
  // emit straight from registers: element index == descending rank
  const float4* pr = (const float4*)(prop + (size_t)img*ATOT*4);
  size_t base = (size_t)img*KTOT + c_CBASE[lvl];
  if (active){
    if (elemA < k){
      cand[base + elemA] = va;
      unsigned gidx = 0xFFFFFFFFu - (unsigned)(va & 0xFFFFFFFFull);
      float4 p = pr[gidx];
      cbox[base + elemA] = make_float4(fminf(fmaxf(p.x,0.f),512.f), fminf(fmaxf(p.y,0.f),512.f),
                                       fminf(fmaxf(p.z,0.f),512.f), fminf(fmaxf(p.w,0.f),512.f));
    }
    if (elemB < k){
      cand[base + elemB] = vb;
      unsigned gidx = 0xFFFFFFFFu - (unsigned)(vb & 0xFFFFFFFFull);
      float4 p = pr[gidx];
      cbox[base + elemB] = make_float4(fminf(fmaxf(p.x,0.f),512.f), fminf(fmaxf(p.y,0.f),512.f),
                                       fminf(fmaxf(p.z,0.f),512.f), fminf(fmaxf(p.w,0.f),512.f));
    }
  }
}

// ---------------- K2: IoU tiles with f32-bounds fast path -> edge lists; zero d_out ----------------
// Exact predicate preserved: inter >= 0.701f*uni implies hit (0.701*(1-2^-24) >
// M_TIE); inter < 0.699f*uni implies not-hit (0.699*(1+2^-24) < M_TIE);
// ambiguous lanes (ratio within ~1e-3 of 0.7, rare) take the exact f64 compare.
extern "C" __global__ void __launch_bounds__(64)
k_mask(const float4* __restrict__ cbox, unsigned* __restrict__ ecnt,
       unsigned* __restrict__ eseg, float4* __restrict__ out4, int out_n4){
  __shared__ float4 colb[64];
  __shared__ float  colA[64];
  int bid = blockIdx.x, lane = threadIdx.x;
  if (bid < 313){
    int i = bid*64 + lane;
    if (i < out_n4) out4[i] = make_float4(0.f,0.f,0.f,0.f);
  }
  int img = bid / TILES_PER_IMG, r = bid % TILES_PER_IMG;
  int lvl = 0;
  while (r >= c_TILEPFX[lvl + 1]) ++lvl;
  int t = r - c_TILEPFX[lvl];
  int G = c_GLVL[lvl], k = c_KSEL[lvl];
  int gi = 0;
  while (t >= G - gi){ t -= G - gi; ++gi; }
  int gj = gi + t;
  int task = img*5 + lvl;
  const float4* cb = cbox + (size_t)img*KTOT + c_CBASE[lvl];

  int jj = gj*64 + lane;
  float4 bb = (jj < k) ? cb[jj] : make_float4(0.f,0.f,0.f,0.f);
  colb[lane] = bb;
  colA[lane] = (bb.z - bb.x) * (bb.w - bb.y);
  __syncthreads();

  int i = gi*64 + lane;
  unsigned long long word = 0ull;
  if (i < k){
    float4 a = cb[i];
    float aarea = (a.z - a.x) * (a.w - a.y);
    for (int j = 0; j < 64; ++j){
      float4 b = colb[j];
      float ix = fminf(a.z, b.z) - fmaxf(a.x, b.x);
      float iy = fminf(a.w, b.w) - fmaxf(a.y, b.y);
      float inter = ix * iy;
      float uni = (aarea + colA[j]) - inter;
      bool base = (ix > 0.f) & (iy > 0.f);
      bool hi  = inter >= 0.701f * uni;
      bool lo  = inter <  0.699f * uni;
      bool hit = base & hi;
      bool amb = base & (!hi) & (!lo);
      if (__any(amb))
        hit = hit | (amb & ((double)inter >= M_TIE * (double)uni));
      word |= hit ? (1ull << j) : 0ull;
    }
    if (gi == gj)
      word &= (lane == 63) ? 0ull : (~0ull << (lane + 1));
  }
  int nb = __popcll(word);
  int pfx = nb;
  for (int d = 1; d < 64; d <<= 1){
    int v = __shfl_up(pfx, d);
    if (lane >= d) pfx += v;
  }
  int total = __shfl(pfx, 63);
  if (total > 0){
    unsigned base = 0;
    if (lane == 0) base = atomicAdd(&ecnt[task*32 + gi], (unsigned)total);
    base = __shfl(base, 0);
    unsigned idx = base + (unsigned)(pfx - nb);
    unsigned* ep = eseg + (size_t)(task*32 + gi)*ESEG;
    while (word){
      int j = __ffsll(word) - 1; word &= word - 1;
      if (idx < ESEG) ep[idx] = ((unsigned)i << 16) | (unsigned)(gj*64 + j);
      ++idx;
    }
  }
}

// ---------------- K3: NMS word-sweep; 4-wave staging, 1-wave exact sweep ----------------
// Staging and compaction use all 4 waves (separated from the sweep by
// __syncthreads). The sweep itself runs entirely in wave 0 on LDS state no
// other wave touches (round-7/11-validated): word w's keep bits are FINAL
// before its suppressions propagate => identical to sequential greedy NMS.
extern "C" __global__ void __launch_bounds__(256)
k_scan(const unsigned long long* __restrict__ cand, const unsigned* __restrict__ ecnt,
       const unsigned* __restrict__ eseg, unsigned long long* __restrict__ clist,
       unsigned* __restrict__ ccnt){
  __shared__ unsigned ledge[6144];          // 24 KB edge cache
  __shared__ unsigned soff[33], wpfx[33];
  __shared__ unsigned long long sm[64];     // intra-word suppression rows
  __shared__ unsigned long long remW[32], keepW[32];
  __shared__ unsigned long long s_hasI;
  int task = blockIdx.x, img = task / 5, lvl = task % 5;
  int k = c_KSEL[lvl], nW = c_GLVL[lvl], tid = threadIdx.x;

  if (tid == 0){
    unsigned s = 0;
    for (int w = 0; w < nW; ++w){ soff[w] = s; s += min(ecnt[task*32 + w], (unsigned)ESEG); }
    soff[nW] = s;
  }
  if (tid < 32) remW[tid] = 0ull;
  __syncthreads();
  // stage all edges into LDS with 4 waves (global fallback beyond 6144)
  for (int w = 0; w < nW; ++w){
    unsigned c = soff[w+1] - soff[w];
    const unsigned* ep = eseg + (size_t)(task*32 + w)*ESEG;
    for (unsigned e = tid; e < c; e += 256){
      unsigned p = soff[w] + e;
      if (p < 6144u) ledge[p] = ep[e];
    }
  }
  __syncthreads();

  if (tid < 64){     // wave 0 runs the exact sequential-greedy word-sweep
    int lane = tid;
    for (int w = 0; w < nW; ++w){
      unsigned c = soff[w+1] - soff[w];
      if (c == 0) continue;
      const unsigned* ep = eseg + (size_t)(task*32 + w)*ESEG;
      sm[lane] = 0ull;
      if (lane == 0) s_hasI = 0ull;
      WAVE_SYNC();
      for (unsigned e = lane; e < c; e += 64){
        unsigned p = soff[w] + e;
        unsigned ed = (p < 6144u) ? ledge[p] : ep[e];
        int i = (int)(ed >> 16), j = (int)(ed & 0xFFFFu);
        if ((j >> 6) == w){
          atomicOr(&sm[i & 63], 1ull << (j & 63));
          atomicOr(&s_hasI, 1ull << (i & 63));
        }
      }
      WAVE_SYNC();
      if (lane == 0){
        unsigned long long r = remW[w];
        unsigned long long x = s_hasI & ~r;
        while (x){
          int i = __ffsll(x) - 1;
          r |= sm[i];
          x &= ~(1ull << i);
          x &= ~r;
        }
        remW[w] = r;
      }
      WAVE_SYNC();
      unsigned long long keep_w = ~remW[w];
      for (unsigned e = lane; e < c; e += 64){
        unsigned p = soff[w] + e;
        unsigned ed = (p < 6144u) ? ledge[p] : ep[e];
        int i = (int)(ed >> 16), j = (int)(ed & 0xFFFFu), wj = j >> 6;
        if (wj != w && ((keep_w >> (i & 63)) & 1ull))
          atomicOr(&remW[wj], 1ull << (j & 63));
      }
      WAVE_SYNC();
    }
    if (lane < 32){
      unsigned long long v = 0ull;
      if (lane < nW){
        int rem = k - lane*64;
        v = (rem >= 64) ? ~0ull : ((1ull << rem) - 1ull);
      }
      keepW[lane] = v & ~remW[lane];
    }
    WAVE_SYNC();
    if (lane == 0){
      unsigned s = 0;
      for (int w = 0; w < nW; ++w){ wpfx[w] = s; s += (unsigned)__popcll(keepW[w]); }
      ccnt[task] = s;
    }
  }
  __syncthreads();
  // compact kept candidates with all 4 waves (preserves sorted order)
  size_t base = (size_t)img*KTOT + c_CBASE[lvl];
  for (int i = tid; i < k; i += 256){
    unsigned long long w = keepW[i >> 6];
    if ((w >> (i & 63)) & 1ull){
      unsigned long long lowmask = (i & 63) ? ((1ull << (i & 63)) - 1ull) : 0ull;
      unsigned rank = wpfx[i >> 6] + (unsigned)__popcll(w & lowmask);
      clist[base + rank] = cand[base + i];
    }
  }
}

// ---------------- K4: 5-way rank merge (no sort), 8 blocks/image ----------------
__device__ __forceinline__ int cntGreater(const unsigned long long* base, int len,
                                          unsigned long long x){
  int lo = 0, hi = len;          // descending array, unique keys
  while (lo < hi){
    int mid = (lo + hi) >> 1;
    if (base[mid] > x) lo = mid + 1; else hi = mid;
  }
  return lo;
}

extern "C" __global__ void __launch_bounds__(1024)
k_merge(const float* __restrict__ prop, const float* __restrict__ obj,
        const unsigned long long* __restrict__ clist, const unsigned* __restrict__ ccnt,
        float* __restrict__ out){
  __shared__ unsigned long long keys[KTOT];   // ~54.4 KB
  __shared__ int loff[6], lcnt[5];
  int img = blockIdx.x >> 3, eighth = blockIdx.x & 7, tid = threadIdx.x;
  if (tid == 0){
    int s = 0;
    for (int l = 0; l < 5; ++l){ lcnt[l] = (int)ccnt[img*5 + l]; loff[l] = s; s += lcnt[l]; }
    loff[5] = s;
  }
  __syncthreads();
  for (int l = 0; l < 5; ++l){
    size_t gb = (size_t)img*KTOT + c_CBASE[l];
    int c = lcnt[l], lo = loff[l];
    for (int e = tid; e < c; e += 1024) keys[lo + e] = clist[gb + e];
  }
  __syncthreads();
  const float4* pr = (const float4*)(prop + (size_t)img*ATOT*4);
  const float*  o  = obj + (size_t)img*ATOT;
  float* ob = out + (size_t)img*POST*4;
  float* os = out + (size_t)NIMG*POST*4 + (size_t)img*POST;
  int tot = loff[5];
  for (int tt = tid; ; tt += 1024){
    int t = 8*tt + eighth;
    if (t >= tot) break;
    int lvl = 0;
    while (t >= loff[lvl + 1]) ++lvl;
    unsigned long long x = keys[t];
    int pos = t - loff[lvl];
    for (int l = 0; l < 5; ++l){
      if (l == lvl) continue;
      pos += cntGreater(keys + loff[l], lcnt[l], x);
    }
    if (pos < POST){
      unsigned gidx = 0xFFFFFFFFu - (unsigned)(x & 0xFFFFFFFFull);
      float4 p = pr[gidx];
      ob[pos*4 + 0] = fminf(fmaxf(p.x, 0.f), 512.f);
      ob[pos*4 + 1] = fminf(fmaxf(p.y, 0.f), 512.f);
      ob[pos*4 + 2] = fminf(fmaxf(p.z, 0.f), 512.f);
      ob[pos*4 + 3] = fminf(fmaxf(p.w, 0.f), 512.f);
      double sgm = 1.0 / (1.0 + exp(-(double)o[gidx]));  // correctly-rounded f32 sigmoid
      os[pos] = (float)sgm;
    }
  }
}

// ---------------- launch ----------------
extern "C" void kernel_launch(void* const* d_in, const int* in_sizes, int n_in,
                              void* d_out, int out_size, void* d_ws, size_t ws_size,
                              hipStream_t stream){
  const float* prop = (const float*)d_in[0];
  const float* obj  = (const float*)d_in[1];
  char* ws = (char*)d_ws;
  // ws layout (bytes):
  unsigned*           ecnt = (unsigned*)(ws);                        // 40*32*4 = 5120
  unsigned*           ccnt = (unsigned*)(ws + 5120);                 // 160 -> 5280 (pad 5632)
  unsigned long long* cand = (unsigned long long*)(ws + 5632);       // 445440 -> 451072
  unsigned long long* clist= (unsigned long long*)(ws + 451072);     // 445440 -> 896512
  float4*             cbox = (float4*)(ws + 896512);                 // 890880 -> 1787392
  unsigned*           eseg = (unsigned*)(ws + 1787392);              // 5242880 -> 7030272

  int out_n4 = out_size / 4;   // 80000 floats = 20000 float4
  hipLaunchKernelGGL(k_select, dim3(40),  dim3(1024), 0, stream, prop, obj, cand, cbox, ecnt);
  hipLaunchKernelGGL(k_mask,   dim3(NTILES), dim3(64), 0, stream, cbox, ecnt, eseg,
                     (float4*)d_out, out_n4);
  hipLaunchKernelGGL(k_scan,   dim3(40),  dim3(256),  0, stream, cand, ecnt, eseg, clist, ccnt);
  hipLaunchKernelGGL(k_merge,  dim3(64),  dim3(1024), 0, stream, prop, obj, clist, ccnt, (float*)d_out);
}